// Round 2
// baseline (706.833 us; speedup 1.0000x reference)
//
#include <hip/hip_runtime.h>
#include <math.h>

// Problem constants (fixed by the reference)
#define B_ROWS 4096
#define C_COLS 32768
#define BLOCK  512
#define NWAVES (BLOCK / 64)            // 8 waves per block
#define NF4    (C_COLS / 4 / BLOCK)    // 16 float4 per thread

typedef float v4f __attribute__((ext_vector_type(4)));

static_assert(NF4 * BLOCK * 4 == C_COLS, "tiling must cover the row exactly");

__device__ __forceinline__ float wave_reduce_sum(float v) {
    #pragma unroll
    for (int off = 32; off > 0; off >>= 1)
        v += __shfl_down(v, off, 64);
    return v;
}

// Block-wide sum over NWAVES waves. `red` must have >= NWAVES floats.
__device__ __forceinline__ float block_reduce_sum(float v, float* red, int tid) {
    const int wid  = tid >> 6;
    const int lane = tid & 63;
    v = wave_reduce_sum(v);
    if (lane == 0) red[wid] = v;
    __syncthreads();
    if (wid == 0) {
        float s = (lane < NWAVES) ? red[lane] : 0.0f;
        #pragma unroll
        for (int off = NWAVES / 2; off > 0; off >>= 1)
            s += __shfl_down(s, off, 64);
        if (lane == 0) red[0] = s;
    }
    __syncthreads();
    return red[0];
}

// Copy-like streaming shape: rolled loops, ~4 float4 live per thread, NORMAL
// cached loads (no nontemporal — pass B re-reads the row from L2/L3; live
// window 4 blk/CU * 256 CU * 131 KB ~= 134 MB < 256 MB Infinity Cache).
// __launch_bounds__(512, 8): 64-VGPR cap -> 4 blocks/CU = 32 waves/CU, the
// same occupancy regime as the 6.3 TB/s float4 copy microbench.
__global__ __launch_bounds__(BLOCK, 8)
void focal_row_kernel(const float* __restrict__ inp,
                      const int*   __restrict__ tgt,
                      float*       __restrict__ row_loss) {
    constexpr float SCALE = 30.0f;
    constexpr float COSM  = 0.9553364891f;   // cos(0.3)
    constexpr float SINM  = 0.2955202067f;   // sin(0.3)

    const int row = blockIdx.x;
    const int tid = threadIdx.x;

    const v4f* __restrict__ rowp = (const v4f*)(inp + (size_t)row * C_COLS);

    __shared__ float red_a[NWAVES];
    __shared__ float red_b[NWAVES];

    // Thread 0 fetches the target element; stays in its registers.
    float xt = 0.0f;
    if (tid == 0) {
        const int ct = tgt[row];
        xt = inp[(size_t)row * C_COLS + ct];
    }

    // ---- Pass A: stream the row (cached), accumulate sum of squares.
    //      Rolled loop: 4 loads in flight/thread; 32 waves/CU provide TLP. ----
    float s0 = 0.0f, s1 = 0.0f, s2 = 0.0f, s3 = 0.0f;
    #pragma unroll 1
    for (int k = 0; k < NF4; k += 4) {
        const v4f a0 = rowp[(k + 0) * BLOCK + tid];
        const v4f a1 = rowp[(k + 1) * BLOCK + tid];
        const v4f a2 = rowp[(k + 2) * BLOCK + tid];
        const v4f a3 = rowp[(k + 3) * BLOCK + tid];
        s0 = fmaf(a0.x, a0.x, s0); s1 = fmaf(a0.y, a0.y, s1);
        s2 = fmaf(a0.z, a0.z, s2); s3 = fmaf(a0.w, a0.w, s3);
        s0 = fmaf(a1.x, a1.x, s0); s1 = fmaf(a1.y, a1.y, s1);
        s2 = fmaf(a1.z, a1.z, s2); s3 = fmaf(a1.w, a1.w, s3);
        s0 = fmaf(a2.x, a2.x, s0); s1 = fmaf(a2.y, a2.y, s1);
        s2 = fmaf(a2.z, a2.z, s2); s3 = fmaf(a2.w, a2.w, s3);
        s0 = fmaf(a3.x, a3.x, s0); s1 = fmaf(a3.y, a3.y, s1);
        s2 = fmaf(a3.z, a3.z, s2); s3 = fmaf(a3.w, a3.w, s3);
    }
    const float sumsq = (s0 + s1) + (s2 + s3);

    const float total_sq = block_reduce_sum(sumsq, red_a, tid);
    const float norm = fmaxf(sqrtf(total_sq), 1e-12f);
    const float inv  = SCALE / norm;

    // ---- Pass B: re-read the row (L2/L3-resident), sum of exp(scale*x/norm).
    //      |logit| <= 30 so fp32 exp is safe without max-subtraction. ----
    float e0 = 0.0f, e1 = 0.0f, e2 = 0.0f, e3 = 0.0f;
    #pragma unroll 1
    for (int k = 0; k < NF4; k += 4) {
        const v4f a0 = rowp[(k + 0) * BLOCK + tid];
        const v4f a1 = rowp[(k + 1) * BLOCK + tid];
        const v4f a2 = rowp[(k + 2) * BLOCK + tid];
        const v4f a3 = rowp[(k + 3) * BLOCK + tid];
        e0 += __expf(a0.x * inv); e1 += __expf(a0.y * inv);
        e2 += __expf(a0.z * inv); e3 += __expf(a0.w * inv);
        e0 += __expf(a1.x * inv); e1 += __expf(a1.y * inv);
        e2 += __expf(a1.z * inv); e3 += __expf(a1.w * inv);
        e0 += __expf(a2.x * inv); e1 += __expf(a2.y * inv);
        e2 += __expf(a2.z * inv); e3 += __expf(a2.w * inv);
        e0 += __expf(a3.x * inv); e1 += __expf(a3.y * inv);
        e2 += __expf(a3.z * inv); e3 += __expf(a3.w * inv);
    }
    const float se = (e0 + e1) + (e2 + e3);
    const float sumexp_full = block_reduce_sum(se, red_b, tid);

    if (tid == 0) {
        const float c  = xt / norm;                         // cos(theta), unclipped
        const float cc = fminf(fmaxf(c, -1.0f + 1e-7f), 1.0f - 1e-7f);
        // cos(theta + m) = c*cos(m) - sqrt(1-c^2)*sin(m)
        const float sin_t = sqrtf(fmaxf(1.0f - cc * cc, 0.0f));
        const float cosm  = cc * COSM - sin_t * SINM;
        const float lt    = SCALE * cosm;                   // target logit

        // replace target term in the partition function
        const float Z  = sumexp_full - __expf(SCALE * c) + __expf(lt);
        const float ce = logf(Z) - lt;                      // -log_softmax[target]
        const float pt = __expf(-ce);
        const float om = 1.0f - pt;
        row_loss[row] = om * om * ce;                       // gamma = 2.0
    }
}

// Single block: mean of 4096 per-row losses -> out[0].
__global__ __launch_bounds__(1024)
void finalize_kernel(const float* __restrict__ row_loss,
                     float*       __restrict__ out) {
    const int tid = threadIdx.x;
    __shared__ float red[16];
    const int wid  = tid >> 6;
    const int lane = tid & 63;
    float s = 0.0f;
    #pragma unroll
    for (int k = 0; k < B_ROWS / 1024; ++k)
        s += row_loss[k * 1024 + tid];
    s = wave_reduce_sum(s);
    if (lane == 0) red[wid] = s;
    __syncthreads();
    if (wid == 0) {
        float t = (lane < 16) ? red[lane] : 0.0f;
        #pragma unroll
        for (int off = 8; off > 0; off >>= 1)
            t += __shfl_down(t, off, 64);
        if (lane == 0) out[0] = t * (1.0f / (float)B_ROWS);
    }
}

extern "C" void kernel_launch(void* const* d_in, const int* in_sizes, int n_in,
                              void* d_out, int out_size, void* d_ws, size_t ws_size,
                              hipStream_t stream) {
    const float* inp = (const float*)d_in[0];
    const int*   tgt = (const int*)d_in[1];
    float*       out = (float*)d_out;
    float*       row_loss = (float*)d_ws;   // 4096 floats = 16 KB of scratch

    focal_row_kernel<<<B_ROWS, BLOCK, 0, stream>>>(inp, tgt, row_loss);
    finalize_kernel<<<1, 1024, 0, stream>>>(row_loss, out);
}